// Round 16
// baseline (26.615 us; speedup 1.0000x reference)
//
#include <hip/hip_runtime.h>

#define BSZ 64
#define LMAX 128
#define DIM 2048
#define NPOS (BSZ * LMAX)   // 8192

struct Ctrl {
    float accum;   // loss sum
    int   count;   // valid-pair count
    int   done2;   // finished loss-blocks
};

// ---------------- kernel 1: delta-projections (+ ctrl init), T-gated --------
// nll(j,k) = softplus(+-(l1-l0)), l1-l0 = dL[j] + dR[k] + beta -> per position
// only TWO dots: dL = h.(WL1-WL0), dR = h.(WR1-WR0).
// 2048 blocks x 512 threads = 8 waves = 2 quads x 4 dim-quarters, 2 positions
// per quad (4 per block). In-flight: 4 h float4 (16 VGPR) + 4 W-diff float4
// (16 VGPR) + addressing ~ 50-55 VGPR -> fits the 64-VGPR cap of
// __launch_bounds__(512,8) WITHOUT spill -> 8 waves/SIMD (32 waves/CU) to
// cover HBM latency + the dependent shfl (DS-pipe) reduction chain.
__global__ __launch_bounds__(512, 8) void proj_kernel(
        const float* __restrict__ enc,
        const float* __restrict__ W,
        const int* __restrict__ mask,
        float* __restrict__ proj,      // [4][NPOS][2] floats
        Ctrl* __restrict__ ctrl) {
    if (blockIdx.x == 0 && threadIdx.x == 0) {
        ctrl->accum = 0.f; ctrl->count = 0; ctrl->done2 = 0;
    }

    const int tid  = threadIdx.x;
    const int wid  = tid >> 6;
    const int lane = tid & 63;
    const int quad = wid >> 2;                      // 0..1
    const int qw   = wid & 3;                       // quarter 0..3
    const int p0   = blockIdx.x * 4 + quad * 2;     // first of 2 positions
    const int b    = blockIdx.x >> 5;               // batch (32 blocks/batch)

    // ---- per-wave turn length ----
    int m = mask[b * LMAX + lane] + mask[b * LMAX + 64 + lane];
    #pragma unroll
    for (int off = 32; off >= 1; off >>= 1) m += __shfl_xor(m, off);
    const int T = m;

    const int pl   = p0 & (LMAX - 1);
    const int nact = min(max(T - pl, 0), 2);
    if (nact == 0) return;

    // ---- W difference-slices: 2 float4 per side ----
    const float4* __restrict__ W4 = (const float4*)W;   // [2*DIM,2] row-major
    float4 dl[2], dr[2];
    #pragma unroll
    for (int it = 0; it < 2; ++it) {
        const int idx = qw * 128 + it * 64 + lane;
        const float4 wl0 = W4[idx * 2];
        const float4 wl1 = W4[idx * 2 + 1];
        const float4 wr0 = W4[1024 + idx * 2];
        const float4 wr1 = W4[1024 + idx * 2 + 1];
        dl[it].x = wl0.y - wl0.x; dl[it].y = wl0.w - wl0.z;
        dl[it].z = wl1.y - wl1.x; dl[it].w = wl1.w - wl1.z;
        dr[it].x = wr0.y - wr0.x; dr[it].y = wr0.w - wr0.z;
        dr[it].z = wr1.y - wr1.x; dr[it].w = wr1.w - wr1.z;
    }

    // ---- gated h loads, both positions issued up front ----
    const float4* __restrict__ h4 = (const float4*)enc;
    const size_t base = (size_t)p0 * (DIM / 4) + qw * 128 + lane;

    float4 h0[2], h1[2];
    #pragma unroll
    for (int q = 0; q < 2; ++q) {
        if (q < nact) {
            const size_t a = base + (size_t)q * (DIM / 4);
            h0[q] = h4[a];
            h1[q] = h4[a + 64];
        }
    }

    float* __restrict__ projf = proj + (size_t)qw * NPOS * 2;

    #pragma unroll
    for (int q = 0; q < 2; ++q) {
        if (q < nact) {
            const float4 a = h0[q], c = h1[q];
            float aL = a.x * dl[0].x + a.y * dl[0].y + a.z * dl[0].z + a.w * dl[0].w
                     + c.x * dl[1].x + c.y * dl[1].y + c.z * dl[1].z + c.w * dl[1].w;
            float aR = a.x * dr[0].x + a.y * dr[0].y + a.z * dr[0].z + a.w * dr[0].w
                     + c.x * dr[1].x + c.y * dr[1].y + c.z * dr[1].z + c.w * dr[1].w;

            // fold (1 shfl level) -> residue lane&1, then 5-step butterfly
            const bool o = (lane & 1);
            const float r = __shfl_xor(o ? aL : aR, 1);
            float u = (o ? aR : aL) + r;
            u += __shfl_xor(u, 2);
            u += __shfl_xor(u, 4);
            u += __shfl_xor(u, 8);
            u += __shfl_xor(u, 16);
            u += __shfl_xor(u, 32);
            if (lane < 2) projf[(size_t)(p0 + q) * 2 + lane] = u;
        }
    }
}

// ---------------- kernel 2: pairwise NLL + finalize ----------------
// 256 blocks x 256 threads; 4 blocks per batch; sums the four quarter-deltas.
// s_d[p] = {dL[p] + beta, dR[p]}; pair: d = s_d[j].x + s_d[k].y;
// nll = softplus(k==j-1 ? -d : d).
__global__ __launch_bounds__(256) void loss_kernel(
        const int* __restrict__ mask,
        const float* __restrict__ proj,
        const float* __restrict__ bias,
        Ctrl* __restrict__ ctrl,
        float* __restrict__ out) {
    __shared__ float2 s_d[LMAX];
    __shared__ float  s_w[4];
    __shared__ int    s_m[4];

    const int b   = blockIdx.x >> 2;
    const int q   = blockIdx.x & 3;
    const int tid = threadIdx.x;

    int m = (tid < LMAX) ? mask[b * LMAX + tid] : 0;
    #pragma unroll
    for (int off = 32; off >= 1; off >>= 1) m += __shfl_xor(m, off);
    if ((tid & 63) == 0) s_m[tid >> 6] = m;
    __syncthreads();

    const int   T    = s_m[0] + s_m[1] + s_m[2] + s_m[3];
    const float beta = bias[1] - bias[0];

    const float2* proj2 = (const float2*)proj;
    if (tid < T) {
        const float2 pa = proj2[0 * NPOS + b * LMAX + tid];
        const float2 pb = proj2[1 * NPOS + b * LMAX + tid];
        const float2 pc = proj2[2 * NPOS + b * LMAX + tid];
        const float2 pd = proj2[3 * NPOS + b * LMAX + tid];
        float2 v;
        v.x = (pa.x + pb.x) + (pc.x + pd.x) + beta;   // dL + beta
        v.y = (pa.y + pb.y) + (pc.y + pd.y);          // dR
        s_d[tid] = v;
    }
    __syncthreads();

    float local = 0.f;
    const int tmax = T << 7;
    for (int t = q * 256 + tid; t < tmax; t += 1024) {
        const int j = t >> 7;
        const int k = t & (LMAX - 1);
        if (k < j) {
            const float dd = s_d[j].x + s_d[k].y;
            const float d  = (k == j - 1) ? -dd : dd;
            local += fmaxf(d, 0.f) + __logf(1.f + __expf(-fabsf(d)));
        }
    }

    #pragma unroll
    for (int off = 32; off >= 1; off >>= 1) local += __shfl_xor(local, off);
    if ((tid & 63) == 0) s_w[tid >> 6] = local;
    __syncthreads();

    if (tid == 0) {
        atomicAdd(&ctrl->accum, s_w[0] + s_w[1] + s_w[2] + s_w[3]);
        if (q == 0) atomicAdd(&ctrl->count, T * (T - 1) / 2);
        __threadfence();
        const int prev = atomicAdd(&ctrl->done2, 1);
        if (prev == 4 * BSZ - 1) {
            const float s = atomicAdd(&ctrl->accum, 0.0f);
            const int   c = atomicAdd(&ctrl->count, 0);
            out[0] = s / (float)(c > 1 ? c : 1);
        }
    }
}

extern "C" void kernel_launch(void* const* d_in, const int* in_sizes, int n_in,
                              void* d_out, int out_size, void* d_ws, size_t ws_size,
                              hipStream_t stream) {
    const float* enc  = (const float*)d_in[0];  // [BSZ, LMAX, DIM] fp32
    const int*   mask = (const int*)d_in[1];    // [BSZ, LMAX] int32
    const float* W    = (const float*)d_in[2];  // [2*DIM, 2] fp32
    const float* bias = (const float*)d_in[3];  // [2] fp32
    float* out = (float*)d_out;

    float* proj = (float*)d_ws;                          // 4*NPOS float2 = 256 KB
    Ctrl*  ctrl = (Ctrl*)((char*)d_ws + 4 * NPOS * 8);

    proj_kernel<<<NPOS / 4, 512, 0, stream>>>(enc, W, mask, proj, ctrl);
    loss_kernel<<<4 * BSZ, 256, 0, stream>>>(mask, proj, bias, ctrl, out);
}

// Round 17
// 24.279 us; speedup vs baseline: 1.0962x; 1.0962x over previous
//
#include <hip/hip_runtime.h>

#define BSZ 64
#define LMAX 128
#define DIM 2048
#define NPOS (BSZ * LMAX)   // 8192

struct Ctrl {
    float accum;   // loss sum
    int   count;   // valid-pair count
    int   done2;   // finished loss-blocks
};

// ---------------- kernel 1: delta-projections (+ ctrl init), T-gated --------
// Round-15 proven base (best: 24.6 us). nll(j,k) = softplus(+-(l1-l0)),
// l1-l0 = dL[j] + dR[k] + beta -> per position only TWO dots.
// 1024 blocks x 512 threads = 8 waves = 2 quads x 4 dim-quarters, 4 positions
// per quad. __launch_bounds__(512,6) = 85-VGPR budget (the (512,8)/64-cap
// spilled in r14; (512,8)+2pos was slower in r16).
// CHANGE vs r15: T via __ballot/__popcll (VALU/SALU) instead of a 6-deep
// dependent __shfl_xor DS chain -- removes ~500 cyc of prologue latency
// before the first h load can issue.
__global__ __launch_bounds__(512, 6) void proj_kernel(
        const float* __restrict__ enc,
        const float* __restrict__ W,
        const int* __restrict__ mask,
        float* __restrict__ proj,      // [4][NPOS][2] floats
        Ctrl* __restrict__ ctrl) {
    if (blockIdx.x == 0 && threadIdx.x == 0) {
        ctrl->accum = 0.f; ctrl->count = 0; ctrl->done2 = 0;
    }

    const int tid  = threadIdx.x;
    const int wid  = tid >> 6;
    const int lane = tid & 63;
    const int quad = wid >> 2;                      // 0..1
    const int qw   = wid & 3;                       // quarter 0..3
    const int p0   = (blockIdx.x * 2 + quad) * 4;   // first of 4 positions
    const int b    = blockIdx.x >> 4;               // batch (16 blocks/batch)

    // ---- per-wave turn length via ballot (no DS ops) ----
    const unsigned long long A = __ballot(mask[b * LMAX + lane] != 0);
    const unsigned long long B = __ballot(mask[b * LMAX + 64 + lane] != 0);
    const int T = __popcll(A) + __popcll(B);

    const int pl   = p0 & (LMAX - 1);
    const int nact = min(max(T - pl, 0), 4);
    if (nact == 0) return;

    // ---- W difference-slices: 2 float4 per side ----
    const float4* __restrict__ W4 = (const float4*)W;   // [2*DIM,2] row-major
    float4 dl[2], dr[2];
    #pragma unroll
    for (int it = 0; it < 2; ++it) {
        const int idx = qw * 128 + it * 64 + lane;
        const float4 wl0 = W4[idx * 2];
        const float4 wl1 = W4[idx * 2 + 1];
        const float4 wr0 = W4[1024 + idx * 2];
        const float4 wr1 = W4[1024 + idx * 2 + 1];
        dl[it].x = wl0.y - wl0.x; dl[it].y = wl0.w - wl0.z;
        dl[it].z = wl1.y - wl1.x; dl[it].w = wl1.w - wl1.z;
        dr[it].x = wr0.y - wr0.x; dr[it].y = wr0.w - wr0.z;
        dr[it].z = wr1.y - wr1.x; dr[it].w = wr1.w - wr1.z;
    }

    // ---- gated h loads, all issued up front ----
    const float4* __restrict__ h4 = (const float4*)enc;
    const size_t base = (size_t)p0 * (DIM / 4) + qw * 128 + lane;

    float4 h0[4], h1[4];
    #pragma unroll
    for (int q = 0; q < 4; ++q) {
        if (q < nact) {
            const size_t a = base + (size_t)q * (DIM / 4);
            h0[q] = h4[a];
            h1[q] = h4[a + 64];
        }
    }

    float* __restrict__ projf = proj + (size_t)qw * NPOS * 2;

    #pragma unroll
    for (int q = 0; q < 4; ++q) {
        if (q < nact) {
            const float4 a = h0[q], c = h1[q];
            float aL = a.x * dl[0].x + a.y * dl[0].y + a.z * dl[0].z + a.w * dl[0].w
                     + c.x * dl[1].x + c.y * dl[1].y + c.z * dl[1].z + c.w * dl[1].w;
            float aR = a.x * dr[0].x + a.y * dr[0].y + a.z * dr[0].z + a.w * dr[0].w
                     + c.x * dr[1].x + c.y * dr[1].y + c.z * dr[1].z + c.w * dr[1].w;

            // fold (1 shfl level) -> residue lane&1, then 5-step butterfly
            const bool o = (lane & 1);
            const float r = __shfl_xor(o ? aL : aR, 1);
            float u = (o ? aR : aL) + r;
            u += __shfl_xor(u, 2);
            u += __shfl_xor(u, 4);
            u += __shfl_xor(u, 8);
            u += __shfl_xor(u, 16);
            u += __shfl_xor(u, 32);
            if (lane < 2) projf[(size_t)(p0 + q) * 2 + lane] = u;
        }
    }
}

// ---------------- kernel 2: pairwise NLL + finalize ----------------
// 256 blocks x 256 threads; 4 blocks per batch; sums the four quarter-deltas.
// T via per-wave ballot (wave0: mask[0..63], wave1: mask[64..127]).
__global__ __launch_bounds__(256) void loss_kernel(
        const int* __restrict__ mask,
        const float* __restrict__ proj,
        const float* __restrict__ bias,
        Ctrl* __restrict__ ctrl,
        float* __restrict__ out) {
    __shared__ float2 s_d[LMAX];
    __shared__ float  s_w[4];
    __shared__ int    s_m[4];

    const int b   = blockIdx.x >> 2;
    const int q   = blockIdx.x & 3;
    const int tid = threadIdx.x;
    const int lane = tid & 63;

    // each of the 4 waves ballots a 64-chunk (waves 2,3 duplicate 0,1; harmless)
    {
        const int widx = ((tid >> 6) & 1) * 64 + lane;
        const unsigned long long bl = __ballot(mask[b * LMAX + widx] != 0);
        if (lane == 0) s_m[tid >> 6] = __popcll(bl);
    }
    __syncthreads();

    const int   T    = s_m[0] + s_m[1];
    const float beta = bias[1] - bias[0];

    const float2* proj2 = (const float2*)proj;
    if (tid < T) {
        const float2 pa = proj2[0 * NPOS + b * LMAX + tid];
        const float2 pb = proj2[1 * NPOS + b * LMAX + tid];
        const float2 pc = proj2[2 * NPOS + b * LMAX + tid];
        const float2 pd = proj2[3 * NPOS + b * LMAX + tid];
        float2 v;
        v.x = (pa.x + pb.x) + (pc.x + pd.x) + beta;   // dL + beta
        v.y = (pa.y + pb.y) + (pc.y + pd.y);          // dR
        s_d[tid] = v;
    }
    __syncthreads();

    float local = 0.f;
    const int tmax = T << 7;
    for (int t = q * 256 + tid; t < tmax; t += 1024) {
        const int j = t >> 7;
        const int k = t & (LMAX - 1);
        if (k < j) {
            const float dd = s_d[j].x + s_d[k].y;
            const float d  = (k == j - 1) ? -dd : dd;
            local += fmaxf(d, 0.f) + __logf(1.f + __expf(-fabsf(d)));
        }
    }

    #pragma unroll
    for (int off = 32; off >= 1; off >>= 1) local += __shfl_xor(local, off);
    if ((tid & 63) == 0) s_w[tid >> 6] = local;
    __syncthreads();

    if (tid == 0) {
        atomicAdd(&ctrl->accum, s_w[0] + s_w[1] + s_w[2] + s_w[3]);
        if (q == 0) atomicAdd(&ctrl->count, T * (T - 1) / 2);
        __threadfence();
        const int prev = atomicAdd(&ctrl->done2, 1);
        if (prev == 4 * BSZ - 1) {
            const float s = atomicAdd(&ctrl->accum, 0.0f);
            const int   c = atomicAdd(&ctrl->count, 0);
            out[0] = s / (float)(c > 1 ? c : 1);
        }
    }
}

extern "C" void kernel_launch(void* const* d_in, const int* in_sizes, int n_in,
                              void* d_out, int out_size, void* d_ws, size_t ws_size,
                              hipStream_t stream) {
    const float* enc  = (const float*)d_in[0];  // [BSZ, LMAX, DIM] fp32
    const int*   mask = (const int*)d_in[1];    // [BSZ, LMAX] int32
    const float* W    = (const float*)d_in[2];  // [2*DIM, 2] fp32
    const float* bias = (const float*)d_in[3];  // [2] fp32
    float* out = (float*)d_out;

    float* proj = (float*)d_ws;                          // 4*NPOS float2 = 256 KB
    Ctrl*  ctrl = (Ctrl*)((char*)d_ws + 4 * NPOS * 8);

    proj_kernel<<<NPOS / 8, 512, 0, stream>>>(enc, W, mask, proj, ctrl);
    loss_kernel<<<4 * BSZ, 256, 0, stream>>>(mask, proj, bias, ctrl, out);
}